// Round 5
// baseline (640.112 us; speedup 1.0000x reference)
//
#include <hip/hip_runtime.h>
#include <hip/hip_cooperative_groups.h>

namespace cg = cooperative_groups;

typedef __bf16 bf16x8 __attribute__((ext_vector_type(8)));
typedef float  f32x4  __attribute__((ext_vector_type(4)));

#define NCH 24
#define HW 128
#define IMG (HW*HW)
#define CHIMG (NCH*IMG)

// d_ws layout: [ping state: 4*CHIMG floats][w1 frags][w2 frags][b2 frags]
#define PW1_OFF ((size_t)(4*CHIMG)*4)
#define PW2_OFF (PW1_OFF + 12*64*8*2)
#define PB2_OFF (PW2_OFF + 4*64*8*2)

// One-time weight packing into MFMA A-fragment layout (bias-1 trick in t=3 slot).
// mfma_f32_16x16x32_bf16: A[row=l%16][k=8*(l/16)+j], B[k][col=l%16], D[row=4*(l/16)+r][col=l%16]
__global__ void nca_pack_weights(const float* __restrict__ w1, const float* __restrict__ b1,
                                 const float* __restrict__ w2, const float* __restrict__ b2,
                                 char* __restrict__ ws)
{
    short* pw1 = (short*)(ws + PW1_OFF);
    short* pw2 = (short*)(ws + PW2_OFF);
    float* pb2 = (float*)(ws + PB2_OFF);
    const int tid = threadIdx.x;
    for (int idx = tid; idx < 12*64*8; idx += 256) {
        int j  = idx & 7;
        int ll = (idx >> 3) & 63;
        int fs = idx >> 9;                  // m*3+s
        int m  = fs / 3, s = fs - 3*m;
        int row = m*16 + (ll & 15);         // h
        int kp  = 32*s + 8*(ll >> 4) + j;   // k' = 4c+t
        int c = kp >> 2, tt = kp & 3;
        float v;
        if (tt < 3) v = w1[row*72 + 3*c + tt];
        else        v = (c == 0) ? b1[row] : 0.f;
        pw1[idx] = (short)__builtin_bit_cast(unsigned short, (__bf16)v);
    }
    for (int idx = tid; idx < 4*64*8; idx += 256) {
        int j  = idx & 7;
        int ll = (idx >> 3) & 63;
        int fs = idx >> 9;                  // m2*2+s2
        int m2 = fs >> 1, s2 = fs & 1;
        int row = m2*16 + (ll & 15);        // o
        int h   = 32*s2 + 8*(ll >> 4) + j;
        float v = (row < 24) ? w2[row*64 + h] : 0.f;
        pw2[idx] = (short)__builtin_bit_cast(unsigned short, (__bf16)v);
    }
    for (int idx = tid; idx < 2*64*4; idx += 256) {
        int r  = idx & 3;
        int ll = (idx >> 2) & 63;
        int m2 = idx >> 8;
        int o  = m2*16 + 4*(ll >> 4) + r;
        pb2[idx] = (o < 24) ? b2[o] : 0.f;
    }
}

// Multi-step NCA kernel. nsteps==32 under a cooperative launch (grid.sync
// between steps); nsteps==1 under a plain launch (fallback, 32 launches).
// LDS: st (state tile, 10368B) and Hb (H transpose, 9216B) share one union —
// residual values are register-saved before Hb overwrites st.
__global__ __launch_bounds__(256, 4) void nca_multi(
    const float* __restrict__ src0, float* __restrict__ dst0, float* __restrict__ alt,
    const char* __restrict__ wsp, const float* __restrict__ masks,
    int nsteps, int step0)
{
    __shared__ __align__(16) char smem[10384];   // max(st 10368, Hb 9216) + pad
    float (*st)[6][18]  = (float(*)[6][18])smem;
    short (*Hb)[16][72] = (short(*)[16][72])smem;

    const short* __restrict__ pw1 = (const short*)(wsp + PW1_OFF);
    const short* __restrict__ pw2 = (const short*)(wsp + PW2_OFF);
    const float* __restrict__ pb2 = (const float*)(wsp + PB2_OFF);

    const int tid = threadIdx.x;
    const int wv  = tid >> 6;
    const int l   = tid & 63;
    const int px  = l & 15;
    const int g   = l >> 4;

    // XCD-contiguous tile mapping: XCD k (bid%8) owns tiles [128k, 128k+128)
    // -> ping-pong state slab (~1.6MB) stays resident in that XCD's L2.
    const int bid = blockIdx.x;
    const int t   = (bid & 7) * 128 + (bid >> 3);
    const int b   = t >> 8;
    const int y0  = ((t >> 3) & 31) * 4;
    const int x0  = (t & 7) * 16;

    const int xc = px + 1;
    const int yc = wv + 1;
    const int x  = x0 + px;
    const int y  = y0 + wv;

    const float* src = src0;
    float*       dst = dst0;

    for (int it = 0; it < nsteps; ++it) {
        const int step = step0 + it;

        // ---- stage state tile (zero "SAME" pad) ----
        const float* sb = src + b * CHIMG;
        for (int idx = tid; idx < NCH*6*18; idx += 256) {
            int c  = idx / 108;
            int r  = idx - c*108;
            int yy = r / 18;
            int xx = r - yy*18;
            int gy = y0 + yy - 1;
            int gx = x0 + xx - 1;
            float v = 0.f;
            if ((unsigned)gy < (unsigned)HW && (unsigned)gx < (unsigned)HW)
                v = sb[c*IMG + gy*HW + gx];
            ((float*)st)[idx] = v;
        }
        __syncthreads();

        // ---- perception directly into B-fragments ----
        bf16x8 pf[3];
        #pragma unroll
        for (int s = 0; s < 3; ++s) {
            #pragma unroll
            for (int cl = 0; cl < 2; ++cl) {
                int c = 8*s + 2*g + cl;
                const float* bp = &st[c][yc-1][xc-1];
                float v00 = bp[0],  v01 = bp[1],  v02 = bp[2];
                float v10 = bp[18], v11 = bp[19], v12 = bp[20];
                float v20 = bp[36], v21 = bp[37], v22 = bp[38];
                pf[s][4*cl+0] = (__bf16)v11;
                pf[s][4*cl+1] = (__bf16)((v02 - v00 + 2.f*(v12 - v10) + v22 - v20) * 0.125f);
                pf[s][4*cl+2] = (__bf16)((v20 - v00 + 2.f*(v21 - v01) + v22 - v02) * 0.125f);
                pf[s][4*cl+3] = (__bf16)((c == 0) ? 1.f : 0.f);
            }
        }

        // ---- save residuals to regs (st will be overwritten by Hb) ----
        float rs0[4], rs1[4];
        #pragma unroll
        for (int r = 0; r < 4; ++r) rs0[r] = st[4*g + r][yc][xc];
        if (g < 2) {
            #pragma unroll
            for (int r = 0; r < 4; ++r) rs1[r] = st[16 + 4*g + r][yc][xc];
        }

        // ---- GEMM1: H^T = w1' x p~^T (A-frags streamed from L1/L2) ----
        f32x4 acc1[4] = {};
        #pragma unroll
        for (int m = 0; m < 4; ++m) {
            #pragma unroll
            for (int s = 0; s < 3; ++s) {
                bf16x8 a = *(const bf16x8*)&pw1[((m*3 + s)*64 + l)*8];
                acc1[m] = __builtin_amdgcn_mfma_f32_16x16x32_bf16(a, pf[s], acc1[m], 0, 0, 0);
            }
        }

        __syncthreads();   // all waves done reading st before Hb overwrites it

        // ---- relu + per-wave transpose (same-wave LDS write->read) ----
        #pragma unroll
        for (int m = 0; m < 4; ++m) {
            #pragma unroll
            for (int rp = 0; rp < 2; ++rp) {
                float lo = fmaxf(acc1[m][2*rp+0], 0.f);
                float hi = fmaxf(acc1[m][2*rp+1], 0.f);
                unsigned int blo = __builtin_bit_cast(unsigned short, (__bf16)lo);
                unsigned int bhi = __builtin_bit_cast(unsigned short, (__bf16)hi);
                int h0 = m*16 + 4*g + 2*rp;
                *(unsigned int*)&Hb[wv][px][h0] = blo | (bhi << 16);
            }
        }

        // ---- GEMM2: delta^T = w2 x relu(H)^T ----
        f32x4 acc2[2] = {};
        #pragma unroll
        for (int s2 = 0; s2 < 2; ++s2) {
            bf16x8 hv = *(const bf16x8*)&Hb[wv][px][8*g + 32*s2];
            #pragma unroll
            for (int m2 = 0; m2 < 2; ++m2) {
                bf16x8 a2 = *(const bf16x8*)&pw2[((m2*2 + s2)*64 + l)*8];
                acc2[m2] = __builtin_amdgcn_mfma_f32_16x16x32_bf16(a2, hv, acc2[m2], 0, 0, 0);
            }
        }

        // ---- epilogue: fire mask + residual + store ----
        float mval = masks[((size_t)step*4 + b)*IMG + y*HW + x];
        float fire = (mval < 0.5f) ? 1.f : 0.f;
        f32x4 b2v0 = *(const f32x4*)&pb2[(0*64 + l)*4];
        f32x4 b2v1 = *(const f32x4*)&pb2[(1*64 + l)*4];
        float* ob = dst + b*CHIMG + y*HW + x;
        #pragma unroll
        for (int r = 0; r < 4; ++r) {
            int o0 = 4*g + r;                   // 0..15
            ob[o0*IMG] = rs0[r] + (acc2[0][r] + b2v0[r]) * fire;
        }
        if (g < 2) {
            #pragma unroll
            for (int r = 0; r < 4; ++r) {
                int o1 = 16 + 4*g + r;          // 16..23
                ob[o1*IMG] = rs1[r] + (acc2[1][r] + b2v1[r]) * fire;
            }
        }

        if (it + 1 < nsteps) {
            cg::this_grid().sync();             // device-scope fence + grid barrier
            src = dst;
            dst = (dst == dst0) ? alt : dst0;
        }
    }
}

extern "C" void kernel_launch(void* const* d_in, const int* in_sizes, int n_in,
                              void* d_out, int out_size, void* d_ws, size_t ws_size,
                              hipStream_t stream) {
    const float* state = (const float*)d_in[0];
    const float* w1    = (const float*)d_in[1];
    const float* b1    = (const float*)d_in[2];
    const float* w2    = (const float*)d_in[3];
    const float* b2    = (const float*)d_in[4];
    const float* masks = (const float*)d_in[5];

    float* out = (float*)d_out;   // odd steps write here; step 31 -> out
    float* ws  = (float*)d_ws;    // even steps write state here; weights past state
    const char* wsc = (const char*)d_ws;

    nca_pack_weights<<<dim3(1), dim3(256), 0, stream>>>(w1, b1, w2, b2, (char*)d_ws);

    // Host-side occupancy gate (pure query — graph-capture safe, deterministic).
    int maxb = 0, ncu = 0, dev = 0;
    (void)hipGetDevice(&dev);
    hipError_t e = hipOccupancyMaxActiveBlocksPerMultiprocessor(&maxb, nca_multi, 256, 0);
    (void)hipDeviceGetAttribute(&ncu, hipDeviceAttributeMultiprocessorCount, dev);

    if (e == hipSuccess && maxb > 0 && ncu > 0 && (long)maxb * ncu >= 1024) {
        int nsteps = 32, step0 = 0;
        void* args[] = {(void*)&state, (void*)&ws, (void*)&out,
                        (void*)&wsc, (void*)&masks, (void*)&nsteps, (void*)&step0};
        hipLaunchCooperativeKernel((const void*)nca_multi,
                                   dim3(1024, 1, 1), dim3(256, 1, 1),
                                   args, 0, stream);
    } else {
        // fallback: 32 plain launches, same kernel, nsteps=1
        for (int s = 0; s < 32; ++s) {
            const float* src = (s == 0) ? state : ((s % 2 == 1) ? ws : out);
            float*       dst = (s % 2 == 0) ? ws : out;
            nca_multi<<<dim3(1024), dim3(256), 0, stream>>>(
                src, dst, (float*)nullptr, wsc, masks, 1, s);
        }
    }
}

// Round 6
// 241.083 us; speedup vs baseline: 2.6552x; 2.6552x over previous
//
#include <hip/hip_runtime.h>

typedef __bf16 bf16x8 __attribute__((ext_vector_type(8)));
typedef float  f32x4  __attribute__((ext_vector_type(4)));

#define NCH 24
#define HW 128
#define IMG (HW*HW)
#define CHIMG (NCH*IMG)
#define SY 8          // staged rows   (4 out + 2*2 halo)
#define SX 20         // staged cols   (16 out + 2*2 halo)
#define S1Y 6         // step-1 result rows
#define S1X 18        // step-1 result cols

// d_ws layout: [ping state: 4*CHIMG floats][w1 frags][w2 frags][b2 frags]
#define PW1_OFF ((size_t)(4*CHIMG)*4)
#define PW2_OFF (PW1_OFF + 12*64*8*2)
#define PB2_OFF (PW2_OFF + 4*64*8*2)

// One-time weight packing into MFMA A-fragment layout (bias-1 trick in t=3 slot).
// mfma_f32_16x16x32_bf16: A[row=l%16][k=8*(l/16)+j], B[k][col=l%16], D[row=4*(l/16)+r][col=l%16]
__global__ void nca_pack_weights(const float* __restrict__ w1, const float* __restrict__ b1,
                                 const float* __restrict__ w2, const float* __restrict__ b2,
                                 char* __restrict__ ws)
{
    short* pw1 = (short*)(ws + PW1_OFF);
    short* pw2 = (short*)(ws + PW2_OFF);
    float* pb2 = (float*)(ws + PB2_OFF);
    const int tid = threadIdx.x;
    for (int idx = tid; idx < 12*64*8; idx += 256) {
        int j  = idx & 7;
        int ll = (idx >> 3) & 63;
        int fs = idx >> 9;                  // m*3+s
        int m  = fs / 3, s = fs - 3*m;
        int row = m*16 + (ll & 15);         // h
        int kp  = 32*s + 8*(ll >> 4) + j;   // k' = 4c+t
        int c = kp >> 2, tt = kp & 3;
        float v;
        if (tt < 3) v = w1[row*72 + 3*c + tt];
        else        v = (c == 0) ? b1[row] : 0.f;
        pw1[idx] = (short)__builtin_bit_cast(unsigned short, (__bf16)v);
    }
    for (int idx = tid; idx < 4*64*8; idx += 256) {
        int j  = idx & 7;
        int ll = (idx >> 3) & 63;
        int fs = idx >> 9;                  // m2*2+s2
        int m2 = fs >> 1, s2 = fs & 1;
        int row = m2*16 + (ll & 15);        // o
        int h   = 32*s2 + 8*(ll >> 4) + j;
        float v = (row < 24) ? w2[row*64 + h] : 0.f;
        pw2[idx] = (short)__builtin_bit_cast(unsigned short, (__bf16)v);
    }
    for (int idx = tid; idx < 2*64*4; idx += 256) {
        int r  = idx & 3;
        int ll = (idx >> 2) & 63;
        int m2 = idx >> 8;
        int o  = m2*16 + 4*(ll >> 4) + r;
        pb2[idx] = (o < 24) ? b2[o] : 0.f;
    }
}

// Fused 2-step NCA (temporal blocking, halo=2). Step A computed on the 6x18
// interior of an 8x20 staged tile (intermediate state lives in f32 LDS);
// step B on the 4x16 core, stored to global. No device-scope sync anywhere.
__global__ __launch_bounds__(256, 4) void nca_step2(
    const float* __restrict__ src, float* __restrict__ dst,
    const char* __restrict__ wsp, const float* __restrict__ masks, int step0)
{
    __shared__ float st_in[NCH][SY][SX];    // 15360 B
    __shared__ float st1[NCH][S1Y][S1X];    // 10368 B
    __shared__ short Hb[4][16][72];         //  9216 B

    const short* __restrict__ pw1 = (const short*)(wsp + PW1_OFF);
    const short* __restrict__ pw2 = (const short*)(wsp + PW2_OFF);
    const float* __restrict__ pb2 = (const float*)(wsp + PB2_OFF);

    const int tid = threadIdx.x;
    const int wv  = tid >> 6;
    const int l   = tid & 63;
    const int px  = l & 15;
    const int g   = l >> 4;

    // XCD-contiguous tile mapping: XCD k (bid%8) owns a contiguous half-batch
    // slab -> ping-pong state stays resident in that XCD's L2.
    const int bid = blockIdx.x;
    const int t   = (bid & 7) * 128 + (bid >> 3);
    const int b   = t >> 8;
    const int y0  = ((t >> 3) & 31) * 4;
    const int x0  = (t & 7) * 16;

    // ---- stage 8x20 tile (zero "SAME" pad) ----
    const float* sb = src + b * CHIMG;
    for (int idx = tid; idx < NCH*SY*SX; idx += 256) {
        int c  = idx / (SY*SX);
        int r  = idx - c * (SY*SX);
        int yy = r / SX;
        int xx = r - yy * SX;
        int gy = y0 + yy - 2;
        int gx = x0 + xx - 2;
        float v = 0.f;
        if ((unsigned)gy < (unsigned)HW && (unsigned)gx < (unsigned)HW)
            v = sb[c*IMG + gy*HW + gx];
        ((float*)st_in)[idx] = v;
    }
    __syncthreads();

    const float* mask1 = masks + ((size_t)step0*4 + b)*IMG;
    const float* mask2 = masks + ((size_t)(step0+1)*4 + b)*IMG;
    f32x4 b2v0 = *(const f32x4*)&pb2[(0*64 + l)*4];
    f32x4 b2v1 = *(const f32x4*)&pb2[(1*64 + l)*4];

    // ================= STEP A: 108 px (6x18) in 7 groups of 16 =================
    for (int itg = 0; itg < 2; ++itg) {
        const int slot = itg*4 + wv;
        if (slot*16 >= S1Y*S1X) break;            // slot 7 fully idle
        const int q     = slot*16 + px;
        const bool lane_valid = (q < S1Y*S1X);
        const int qq = lane_valid ? q : 0;
        const int r1 = qq / S1X;                  // st1 row
        const int c1 = qq - r1*S1X;               // st1 col
        const int sy = r1 + 1;                    // st_in center coords
        const int sx = c1 + 1;

        // perception into B-fragments
        bf16x8 pf[3];
        #pragma unroll
        for (int s = 0; s < 3; ++s) {
            #pragma unroll
            for (int cl = 0; cl < 2; ++cl) {
                int c = 8*s + 2*g + cl;
                const float* bp = &st_in[c][sy-1][sx-1];
                float v00 = bp[0],    v01 = bp[1],    v02 = bp[2];
                float v10 = bp[SX],   v11 = bp[SX+1], v12 = bp[SX+2];
                float v20 = bp[2*SX], v21 = bp[2*SX+1], v22 = bp[2*SX+2];
                pf[s][4*cl+0] = (__bf16)v11;
                pf[s][4*cl+1] = (__bf16)((v02 - v00 + 2.f*(v12 - v10) + v22 - v20) * 0.125f);
                pf[s][4*cl+2] = (__bf16)((v20 - v00 + 2.f*(v21 - v01) + v22 - v02) * 0.125f);
                pf[s][4*cl+3] = (__bf16)((c == 0) ? 1.f : 0.f);
            }
        }

        // GEMM1
        f32x4 acc1[4] = {};
        #pragma unroll
        for (int m = 0; m < 4; ++m) {
            #pragma unroll
            for (int s = 0; s < 3; ++s) {
                bf16x8 a = *(const bf16x8*)&pw1[((m*3 + s)*64 + l)*8];
                acc1[m] = __builtin_amdgcn_mfma_f32_16x16x32_bf16(a, pf[s], acc1[m], 0, 0, 0);
            }
        }
        // relu + per-wave transpose (same-wave LDS write->read)
        #pragma unroll
        for (int m = 0; m < 4; ++m) {
            #pragma unroll
            for (int rp = 0; rp < 2; ++rp) {
                float lo = fmaxf(acc1[m][2*rp+0], 0.f);
                float hi = fmaxf(acc1[m][2*rp+1], 0.f);
                unsigned int blo = __builtin_bit_cast(unsigned short, (__bf16)lo);
                unsigned int bhi = __builtin_bit_cast(unsigned short, (__bf16)hi);
                int h0 = m*16 + 4*g + 2*rp;
                *(unsigned int*)&Hb[wv][px][h0] = blo | (bhi << 16);
            }
        }
        // GEMM2
        f32x4 acc2[2] = {};
        #pragma unroll
        for (int s2 = 0; s2 < 2; ++s2) {
            bf16x8 hv = *(const bf16x8*)&Hb[wv][px][8*g + 32*s2];
            #pragma unroll
            for (int m2 = 0; m2 < 2; ++m2) {
                bf16x8 a2 = *(const bf16x8*)&pw2[((m2*2 + s2)*64 + l)*8];
                acc2[m2] = __builtin_amdgcn_mfma_f32_16x16x32_bf16(a2, hv, acc2[m2], 0, 0, 0);
            }
        }

        // epilogue into st1 (zero for out-of-image px)
        const int gy = y0 + sy - 2;
        const int gx = x0 + sx - 2;
        const bool inimg = (unsigned)gy < (unsigned)HW && (unsigned)gx < (unsigned)HW;
        const int cy = inimg ? gy : 0;
        const int cx = inimg ? gx : 0;
        float mval = mask1[cy*HW + cx];
        float fire = (inimg && mval < 0.5f) ? 1.f : 0.f;
        float keep = inimg ? 1.f : 0.f;
        if (lane_valid) {
            #pragma unroll
            for (int r = 0; r < 4; ++r) {
                int o0 = 4*g + r;
                st1[o0][r1][c1] = keep * (st_in[o0][sy][sx] + (acc2[0][r] + b2v0[r]) * fire);
            }
            if (g < 2) {
                #pragma unroll
                for (int r = 0; r < 4; ++r) {
                    int o1 = 16 + 4*g + r;
                    st1[o1][r1][c1] = keep * (st_in[o1][sy][sx] + (acc2[1][r] + b2v1[r]) * fire);
                }
            }
        }
    }
    __syncthreads();   // all step-A writes visible before step-B reads

    // ================= STEP B: 4x16 core, wave wv = output row y0+wv =================
    {
        const int r1 = wv + 1;         // st1 center coords
        const int c1 = px + 1;

        bf16x8 pf[3];
        #pragma unroll
        for (int s = 0; s < 3; ++s) {
            #pragma unroll
            for (int cl = 0; cl < 2; ++cl) {
                int c = 8*s + 2*g + cl;
                const float* bp = &st1[c][r1-1][c1-1];
                float v00 = bp[0],     v01 = bp[1],      v02 = bp[2];
                float v10 = bp[S1X],   v11 = bp[S1X+1],  v12 = bp[S1X+2];
                float v20 = bp[2*S1X], v21 = bp[2*S1X+1], v22 = bp[2*S1X+2];
                pf[s][4*cl+0] = (__bf16)v11;
                pf[s][4*cl+1] = (__bf16)((v02 - v00 + 2.f*(v12 - v10) + v22 - v20) * 0.125f);
                pf[s][4*cl+2] = (__bf16)((v20 - v00 + 2.f*(v21 - v01) + v22 - v02) * 0.125f);
                pf[s][4*cl+3] = (__bf16)((c == 0) ? 1.f : 0.f);
            }
        }

        f32x4 acc1[4] = {};
        #pragma unroll
        for (int m = 0; m < 4; ++m) {
            #pragma unroll
            for (int s = 0; s < 3; ++s) {
                bf16x8 a = *(const bf16x8*)&pw1[((m*3 + s)*64 + l)*8];
                acc1[m] = __builtin_amdgcn_mfma_f32_16x16x32_bf16(a, pf[s], acc1[m], 0, 0, 0);
            }
        }
        #pragma unroll
        for (int m = 0; m < 4; ++m) {
            #pragma unroll
            for (int rp = 0; rp < 2; ++rp) {
                float lo = fmaxf(acc1[m][2*rp+0], 0.f);
                float hi = fmaxf(acc1[m][2*rp+1], 0.f);
                unsigned int blo = __builtin_bit_cast(unsigned short, (__bf16)lo);
                unsigned int bhi = __builtin_bit_cast(unsigned short, (__bf16)hi);
                int h0 = m*16 + 4*g + 2*rp;
                *(unsigned int*)&Hb[wv][px][h0] = blo | (bhi << 16);
            }
        }
        f32x4 acc2[2] = {};
        #pragma unroll
        for (int s2 = 0; s2 < 2; ++s2) {
            bf16x8 hv = *(const bf16x8*)&Hb[wv][px][8*g + 32*s2];
            #pragma unroll
            for (int m2 = 0; m2 < 2; ++m2) {
                bf16x8 a2 = *(const bf16x8*)&pw2[((m2*2 + s2)*64 + l)*8];
                acc2[m2] = __builtin_amdgcn_mfma_f32_16x16x32_bf16(a2, hv, acc2[m2], 0, 0, 0);
            }
        }

        const int x = x0 + px;
        const int y = y0 + wv;
        float mval = mask2[y*HW + x];
        float fire = (mval < 0.5f) ? 1.f : 0.f;
        float* ob = dst + b*CHIMG + y*HW + x;
        #pragma unroll
        for (int r = 0; r < 4; ++r) {
            int o0 = 4*g + r;
            ob[o0*IMG] = st1[o0][r1][c1] + (acc2[0][r] + b2v0[r]) * fire;
        }
        if (g < 2) {
            #pragma unroll
            for (int r = 0; r < 4; ++r) {
                int o1 = 16 + 4*g + r;
                ob[o1*IMG] = st1[o1][r1][c1] + (acc2[1][r] + b2v1[r]) * fire;
            }
        }
    }
}

extern "C" void kernel_launch(void* const* d_in, const int* in_sizes, int n_in,
                              void* d_out, int out_size, void* d_ws, size_t ws_size,
                              hipStream_t stream) {
    const float* state = (const float*)d_in[0];
    const float* w1    = (const float*)d_in[1];
    const float* b1    = (const float*)d_in[2];
    const float* w2    = (const float*)d_in[3];
    const float* b2    = (const float*)d_in[4];
    const float* masks = (const float*)d_in[5];

    float* out = (float*)d_out;
    float* ws  = (float*)d_ws;
    const char* wsc = (const char*)d_ws;

    nca_pack_weights<<<dim3(1), dim3(256), 0, stream>>>(w1, b1, w2, b2, (char*)d_ws);

    // 16 fused launches, each advancing 2 steps. Launch i: steps 2i, 2i+1.
    for (int i = 0; i < 16; ++i) {
        const float* src = (i == 0) ? state : ((i & 1) ? ws : out);
        float*       dst = (i & 1) ? out : ws;
        nca_step2<<<dim3(1024), dim3(256), 0, stream>>>(src, dst, wsc, masks, 2*i);
    }
}

// Round 7
// 227.265 us; speedup vs baseline: 2.8166x; 1.0608x over previous
//
#include <hip/hip_runtime.h>

typedef __bf16 bf16x8 __attribute__((ext_vector_type(8)));
typedef float  f32x4  __attribute__((ext_vector_type(4)));

#define NCH 24
#define CP  26        // padded channel stride (floats) -> conflict-free, 8B-aligned pairs
#define HW 128
#define IMG (HW*HW)
#define CHIMG (NCH*IMG)
#define SXP 20        // staged x (16 + 2*2 halo)
#define SYP 8         // staged y (4 + 2*2 halo)
#define S1XP 18       // step-1 intermediate x
#define S1YP 6        // step-1 intermediate y
#define S1N (S1XP*S1YP)   // 108

// d_ws layout: [ping state: 4*CHIMG floats][w1 frags][w2 frags][b2 frags]
#define PW1_OFF ((size_t)(4*CHIMG)*4)
#define PW2_OFF (PW1_OFF + 12*64*8*2)
#define PB2_OFF (PW2_OFF + 4*64*8*2)

// One-time weight packing into MFMA A-fragment layout (bias-1 trick in t=3 slot).
// mfma_f32_16x16x32_bf16: A[row=l%16][k=8*(l/16)+j], B[k][col=l%16], D[row=4*(l/16)+r][col=l%16]
__global__ void nca_pack_weights(const float* __restrict__ w1, const float* __restrict__ b1,
                                 const float* __restrict__ w2, const float* __restrict__ b2,
                                 char* __restrict__ ws)
{
    short* pw1 = (short*)(ws + PW1_OFF);
    short* pw2 = (short*)(ws + PW2_OFF);
    float* pb2 = (float*)(ws + PB2_OFF);
    const int tid = threadIdx.x;
    for (int idx = tid; idx < 12*64*8; idx += 256) {
        int j  = idx & 7;
        int ll = (idx >> 3) & 63;
        int fs = idx >> 9;                  // m*3+s
        int m  = fs / 3, s = fs - 3*m;
        int row = m*16 + (ll & 15);         // h
        int kp  = 32*s + 8*(ll >> 4) + j;   // k' = 4c+t
        int c = kp >> 2, tt = kp & 3;
        float v;
        if (tt < 3) v = w1[row*72 + 3*c + tt];
        else        v = (c == 0) ? b1[row] : 0.f;
        pw1[idx] = (short)__builtin_bit_cast(unsigned short, (__bf16)v);
    }
    for (int idx = tid; idx < 4*64*8; idx += 256) {
        int j  = idx & 7;
        int ll = (idx >> 3) & 63;
        int fs = idx >> 9;                  // m2*2+s2
        int m2 = fs >> 1, s2 = fs & 1;
        int row = m2*16 + (ll & 15);        // o
        int h   = 32*s2 + 8*(ll >> 4) + j;
        float v = (row < 24) ? w2[row*64 + h] : 0.f;
        pw2[idx] = (short)__builtin_bit_cast(unsigned short, (__bf16)v);
    }
    for (int idx = tid; idx < 2*64*4; idx += 256) {
        int r  = idx & 3;
        int ll = (idx >> 2) & 63;
        int m2 = idx >> 8;
        int o  = m2*16 + 4*(ll >> 4) + r;
        pb2[idx] = (o < 24) ? b2[o] : 0.f;
    }
}

// One NCA micro-step for one pixel-slot: perception (float2 channel-pair loads
// from a pixel-major LDS tile) -> GEMM1 -> relu/transpose (per-wave Hb) -> GEMM2.
// Returns delta accumulators (without b2) in d0 (ch 0..15 as 4g+r) and d1 (16..23).
template<int XP>
__device__ __forceinline__ void nca_mlp(
    const float* __restrict__ stsrc, int sy, int sx,
    int l, int px, int g, int wv, short (*Hb)[16][72],
    const short* __restrict__ pw1, const short* __restrict__ pw2,
    f32x4& d0, f32x4& d1)
{
    const float* base = stsrc + ((sy-1)*XP + (sx-1))*CP + 2*g;
    bf16x8 pf[3];
    #pragma unroll
    for (int s = 0; s < 3; ++s) {
        #define LDV(dy,dx) (*(const float2*)(base + ((dy)*XP + (dx))*CP + 8*s))
        float2 v00=LDV(0,0), v01=LDV(0,1), v02=LDV(0,2);
        float2 v10=LDV(1,0), v11=LDV(1,1), v12=LDV(1,2);
        float2 v20=LDV(2,0), v21=LDV(2,1), v22=LDV(2,2);
        #undef LDV
        float gxx = (v02.x - v00.x + 2.f*(v12.x - v10.x) + v22.x - v20.x) * 0.125f;
        float gxy = (v02.y - v00.y + 2.f*(v12.y - v10.y) + v22.y - v20.y) * 0.125f;
        float gyx = (v20.x - v00.x + 2.f*(v21.x - v01.x) + v22.x - v02.x) * 0.125f;
        float gyy = (v20.y - v00.y + 2.f*(v21.y - v01.y) + v22.y - v02.y) * 0.125f;
        pf[s][0] = (__bf16)v11.x;
        pf[s][1] = (__bf16)gxx;
        pf[s][2] = (__bf16)gyx;
        pf[s][3] = (__bf16)((s == 0 && g == 0) ? 1.f : 0.f);   // bias-1 slot (c==0)
        pf[s][4] = (__bf16)v11.y;
        pf[s][5] = (__bf16)gxy;
        pf[s][6] = (__bf16)gyy;
        pf[s][7] = (__bf16)0.f;
    }

    // GEMM1: H^T = w1' x p~^T
    f32x4 acc1[4] = {};
    #pragma unroll
    for (int m = 0; m < 4; ++m) {
        #pragma unroll
        for (int s = 0; s < 3; ++s) {
            bf16x8 a = *(const bf16x8*)&pw1[((m*3 + s)*64 + l)*8];
            acc1[m] = __builtin_amdgcn_mfma_f32_16x16x32_bf16(a, pf[s], acc1[m], 0, 0, 0);
        }
    }

    // relu + per-wave transpose: 4 shorts (rows h0..h0+3) per 8B write
    #pragma unroll
    for (int m = 0; m < 4; ++m) {
        unsigned int b0 = __builtin_bit_cast(unsigned short, (__bf16)fmaxf(acc1[m][0], 0.f));
        unsigned int b1_ = __builtin_bit_cast(unsigned short, (__bf16)fmaxf(acc1[m][1], 0.f));
        unsigned int b2_ = __builtin_bit_cast(unsigned short, (__bf16)fmaxf(acc1[m][2], 0.f));
        unsigned int b3 = __builtin_bit_cast(unsigned short, (__bf16)fmaxf(acc1[m][3], 0.f));
        uint2 w; w.x = b0 | (b1_ << 16); w.y = b2_ | (b3 << 16);
        *(uint2*)&Hb[wv][px][m*16 + 4*g] = w;      // 8B-aligned
    }
    // same-wave write->read: compiler inserts lgkmcnt wait, no barrier needed

    // GEMM2: delta^T = w2 x relu(H)^T
    f32x4 acc2[2] = {};
    #pragma unroll
    for (int s2 = 0; s2 < 2; ++s2) {
        bf16x8 hv = *(const bf16x8*)&Hb[wv][px][8*g + 32*s2];
        #pragma unroll
        for (int m2 = 0; m2 < 2; ++m2) {
            bf16x8 a2 = *(const bf16x8*)&pw2[((m2*2 + s2)*64 + l)*8];
            acc2[m2] = __builtin_amdgcn_mfma_f32_16x16x32_bf16(a2, hv, acc2[m2], 0, 0, 0);
        }
    }
    d0 = acc2[0];
    d1 = acc2[1];
}

// Fused 2-step NCA (temporal blocking, halo=2), pixel-major LDS tiles.
__global__ __launch_bounds__(256, 4) void nca_step2(
    const float* __restrict__ src, float* __restrict__ dst,
    const char* __restrict__ wsp, const float* __restrict__ masks, int step0)
{
    __shared__ __align__(16) float st_in[SYP*SXP*CP];   // 16640 B, [y][x][c]
    __shared__ __align__(16) float st1[S1YP*S1XP*CP];   // 11232 B
    __shared__ __align__(16) short Hb[4][16][72];       //  9216 B

    const short* __restrict__ pw1 = (const short*)(wsp + PW1_OFF);
    const short* __restrict__ pw2 = (const short*)(wsp + PW2_OFF);
    const float* __restrict__ pb2 = (const float*)(wsp + PB2_OFF);

    const int tid = threadIdx.x;
    const int wv  = tid >> 6;
    const int l   = tid & 63;
    const int px  = l & 15;
    const int g   = l >> 4;

    // XCD-contiguous tile mapping: XCD k (bid%8) owns a contiguous half-batch
    // slab -> ping-pong state stays resident in that XCD's L2.
    const int bid = blockIdx.x;
    const int t   = (bid & 7) * 128 + (bid >> 3);
    const int b   = t >> 8;
    const int y0  = ((t >> 3) & 31) * 4;
    const int x0  = (t & 7) * 16;

    // ---- stage 8x20 tile, pixel-major (zero "SAME" pad) ----
    const float* sb = src + b * CHIMG;
    for (int idx = tid; idx < NCH*SYP*SXP; idx += 256) {
        int xx = idx % SXP;
        int tt = idx / SXP;
        int yy = tt % SYP;
        int c  = tt / SYP;
        int gy = y0 + yy - 2;
        int gx = x0 + xx - 2;
        float v = 0.f;
        if ((unsigned)gy < (unsigned)HW && (unsigned)gx < (unsigned)HW)
            v = sb[c*IMG + gy*HW + gx];
        st_in[(yy*SXP + xx)*CP + c] = v;
    }
    __syncthreads();

    const float* mask1 = masks + ((size_t)step0*4 + b)*IMG;
    const float* mask2 = masks + ((size_t)(step0+1)*4 + b)*IMG;
    f32x4 b2v0 = *(const f32x4*)&pb2[(0*64 + l)*4];
    f32x4 b2v1 = *(const f32x4*)&pb2[(1*64 + l)*4];

    // ============ STEP A: 108 px (6x18) in 7 slots of 16 ============
    for (int itg = 0; itg < 2; ++itg) {
        const int slot = itg*4 + wv;
        if (slot*16 >= S1N) break;                 // slot 7 idle
        const int q  = slot*16 + px;
        const bool lane_valid = (q < S1N);
        const int qq = lane_valid ? q : 0;
        const int r1 = qq / S1XP;
        const int c1 = qq - r1*S1XP;

        f32x4 d0, d1;
        nca_mlp<SXP>(st_in, r1+1, c1+1, l, px, g, wv, Hb, pw1, pw2, d0, d1);

        // epilogue into st1 (zero out-of-image px)
        const int gy = y0 + r1 - 1;
        const int gx = x0 + c1 - 1;
        const bool inimg = (unsigned)gy < (unsigned)HW && (unsigned)gx < (unsigned)HW;
        const int cy = inimg ? gy : 0;
        const int cx = inimg ? gx : 0;
        float mval = mask1[cy*HW + cx];
        float fire = (inimg && mval < 0.5f) ? 1.f : 0.f;
        float keep = inimg ? 1.f : 0.f;
        if (lane_valid) {
            const int pc  = ((r1+1)*SXP + (c1+1))*CP;   // st_in center pixel
            const int pd  = (r1*S1XP + c1)*CP;          // st1 pixel
            float2 ra = *(const float2*)&st_in[pc + 4*g];
            float2 rb = *(const float2*)&st_in[pc + 4*g + 2];
            float2 o0, o1;
            o0.x = keep * (ra.x + (d0[0] + b2v0[0]) * fire);
            o0.y = keep * (ra.y + (d0[1] + b2v0[1]) * fire);
            o1.x = keep * (rb.x + (d0[2] + b2v0[2]) * fire);
            o1.y = keep * (rb.y + (d0[3] + b2v0[3]) * fire);
            *(float2*)&st1[pd + 4*g]     = o0;
            *(float2*)&st1[pd + 4*g + 2] = o1;
            if (g < 2) {
                float2 rc = *(const float2*)&st_in[pc + 16 + 4*g];
                float2 rd = *(const float2*)&st_in[pc + 16 + 4*g + 2];
                float2 o2, o3;
                o2.x = keep * (rc.x + (d1[0] + b2v1[0]) * fire);
                o2.y = keep * (rc.y + (d1[1] + b2v1[1]) * fire);
                o3.x = keep * (rd.x + (d1[2] + b2v1[2]) * fire);
                o3.y = keep * (rd.y + (d1[3] + b2v1[3]) * fire);
                *(float2*)&st1[pd + 16 + 4*g]     = o2;
                *(float2*)&st1[pd + 16 + 4*g + 2] = o3;
            }
        }
    }
    __syncthreads();   // all step-A writes visible before step-B reads

    // ============ STEP B: 4x16 core ============
    {
        f32x4 d0, d1;
        nca_mlp<S1XP>(st1, wv+1, px+1, l, px, g, wv, Hb, pw1, pw2, d0, d1);

        const int x = x0 + px;
        const int y = y0 + wv;
        float mval = mask2[y*HW + x];
        float fire = (mval < 0.5f) ? 1.f : 0.f;
        const int pc = ((wv+1)*S1XP + (px+1))*CP;
        float* ob = dst + b*CHIMG + y*HW + x;

        float2 ra = *(const float2*)&st1[pc + 4*g];
        float2 rb = *(const float2*)&st1[pc + 4*g + 2];
        ob[(4*g + 0)*IMG] = ra.x + (d0[0] + b2v0[0]) * fire;
        ob[(4*g + 1)*IMG] = ra.y + (d0[1] + b2v0[1]) * fire;
        ob[(4*g + 2)*IMG] = rb.x + (d0[2] + b2v0[2]) * fire;
        ob[(4*g + 3)*IMG] = rb.y + (d0[3] + b2v0[3]) * fire;
        if (g < 2) {
            float2 rc = *(const float2*)&st1[pc + 16 + 4*g];
            float2 rd = *(const float2*)&st1[pc + 16 + 4*g + 2];
            ob[(16 + 4*g + 0)*IMG] = rc.x + (d1[0] + b2v1[0]) * fire;
            ob[(16 + 4*g + 1)*IMG] = rc.y + (d1[1] + b2v1[1]) * fire;
            ob[(16 + 4*g + 2)*IMG] = rd.x + (d1[2] + b2v1[2]) * fire;
            ob[(16 + 4*g + 3)*IMG] = rd.y + (d1[3] + b2v1[3]) * fire;
        }
    }
}

extern "C" void kernel_launch(void* const* d_in, const int* in_sizes, int n_in,
                              void* d_out, int out_size, void* d_ws, size_t ws_size,
                              hipStream_t stream) {
    const float* state = (const float*)d_in[0];
    const float* w1    = (const float*)d_in[1];
    const float* b1    = (const float*)d_in[2];
    const float* w2    = (const float*)d_in[3];
    const float* b2    = (const float*)d_in[4];
    const float* masks = (const float*)d_in[5];

    float* out = (float*)d_out;
    float* ws  = (float*)d_ws;
    const char* wsc = (const char*)d_ws;

    nca_pack_weights<<<dim3(1), dim3(256), 0, stream>>>(w1, b1, w2, b2, (char*)d_ws);

    // 16 fused launches, each advancing 2 steps. Launch i: steps 2i, 2i+1.
    for (int i = 0; i < 16; ++i) {
        const float* src = (i == 0) ? state : ((i & 1) ? ws : out);
        float*       dst = (i & 1) ? out : ws;
        nca_step2<<<dim3(1024), dim3(256), 0, stream>>>(src, dst, wsc, masks, 2*i);
    }
}